// Round 2
// baseline (761.904 us; speedup 1.0000x reference)
//
#include <hip/hip_runtime.h>

#define NN 200000
#define DD 16
#define KK 16
#define FF 33   // 2*DD + 1

constexpr float EPSV = 1e-5f;

__device__ __forceinline__ float leakyf(float v) { return fmaxf(v, 0.2f * v); }

// fp32 -> bf16 round-to-nearest-even
__device__ __forceinline__ unsigned short f2bf(float f) {
    unsigned u = __float_as_uint(f);
    u += 0x7FFFu + ((u >> 16) & 1u);
    return (unsigned short)(u >> 16);
}
// unpack bf16 pair packed in a u32 (little-endian: low half = even element)
__device__ __forceinline__ float bflo(unsigned u) { return __uint_as_float(u << 16); }
__device__ __forceinline__ float bfhi(unsigned u) { return __uint_as_float(u & 0xFFFF0000u); }

// ---- pre-pass: residual(d_out) = y ; tbl0 = bf16(y) ----
__global__ __launch_bounds__(256) void prep_kernel(
    const float* __restrict__ y, float* __restrict__ resid,
    unsigned short* __restrict__ tbl)
{
    const int i = blockIdx.x * 256 + threadIdx.x;   // 800000 float4-groups
    if (i >= NN * 4) return;
    const float4 v = reinterpret_cast<const float4*>(y)[i];
    reinterpret_cast<float4*>(resid)[i] = v;
    ushort4 t;
    t.x = f2bf(v.x); t.y = f2bf(v.y); t.z = f2bf(v.z); t.w = f2bf(v.w);
    reinterpret_cast<ushort4*>(tbl)[i] = t;
}

// ---- one message-passing layer: 4 lanes per node, in-place fp32 residual ----
__global__ __launch_bounds__(256) void layer_kernel(
    float*       __restrict__ resid,   // N x D fp32, read self + write out (in-place)
    const unsigned short* __restrict__ tin,   // N x D bf16 gather table (prev layer)
    unsigned short*       __restrict__ tout,  // N x D bf16 gather table (this layer)
    const float* __restrict__ dists,   // N x K
    const int*   __restrict__ idx,     // N x K (int32)
    const float* __restrict__ W1,      // F x F
    const float* __restrict__ bb1,     // F
    const float* __restrict__ W2,      // F x D
    const float* __restrict__ bb2,     // D
    const float* __restrict__ gnw,     // D
    const float* __restrict__ gnb)     // D
{
    const int t = blockIdx.x * 256 + threadIdx.x;
    const int n = t >> 2;      // node
    const int s = t & 3;       // quarter: neighbors 4s..4s+3
    if (n >= NN) return;

    // ---- self row fp32 (4 lanes of a node read the same 64B; coalescer merges) ----
    const float4* sv = reinterpret_cast<const float4*>(resid + (size_t)n * DD);
    const float4 f0 = sv[0], f1 = sv[1], f2 = sv[2], f3 = sv[3];
    float self_[DD];
    self_[0]=f0.x; self_[1]=f0.y; self_[2]=f0.z; self_[3]=f0.w;
    self_[4]=f1.x; self_[5]=f1.y; self_[6]=f1.z; self_[7]=f1.w;
    self_[8]=f2.x; self_[9]=f2.y; self_[10]=f2.z; self_[11]=f2.w;
    self_[12]=f3.x; self_[13]=f3.y; self_[14]=f3.z; self_[15]=f3.w;

    // ---- this lane's 4 idx + 4 dists (perfectly coalesced: lane*16B) ----
    const int4   nix = *reinterpret_cast<const int4*>(idx + (size_t)n * KK + s * 4);
    const float4 dq  = *reinterpret_cast<const float4*>(dists + (size_t)n * KK + s * 4);

    // ---- issue all 4 neighbor-row gathers up front (bf16 rows, 2 x 16B each) ----
    const uint4* g0 = reinterpret_cast<const uint4*>(tin + (size_t)nix.x * DD);
    const uint4* g1 = reinterpret_cast<const uint4*>(tin + (size_t)nix.y * DD);
    const uint4* g2 = reinterpret_cast<const uint4*>(tin + (size_t)nix.z * DD);
    const uint4* g3 = reinterpret_cast<const uint4*>(tin + (size_t)nix.w * DD);
    const uint4 ra0 = g0[0], rb0 = g0[1];
    const uint4 ra1 = g1[0], rb1 = g1[1];
    const uint4 ra2 = g2[0], rb2 = g2[1];
    const uint4 ra3 = g3[0], rb3 = g3[1];

    // ---- base[g] = b1[g] + sum_d self[d] * W1[d][g] ----
    float base[FF];
#pragma unroll
    for (int g = 0; g < FF; ++g) base[g] = bb1[g];
#pragma unroll
    for (int d = 0; d < DD; ++d) {
        const float x = self_[d];
#pragma unroll
        for (int g = 0; g < FF; ++g)
            base[g] = fmaf(x, W1[d * FF + g], base[g]);
    }

    float hsum[FF];
#pragma unroll
    for (int g = 0; g < FF; ++g) hsum[g] = 0.0f;

    // ---- per-neighbor body (macro keeps all register names compile-time) ----
#define DO_NB(RA, RB, DK)                                                    \
    {                                                                        \
        float nb[DD];                                                        \
        nb[0]=bflo(RA.x);  nb[1]=bfhi(RA.x);  nb[2]=bflo(RA.y);  nb[3]=bfhi(RA.y);  \
        nb[4]=bflo(RA.z);  nb[5]=bfhi(RA.z);  nb[6]=bflo(RA.w);  nb[7]=bfhi(RA.w);  \
        nb[8]=bflo(RB.x);  nb[9]=bfhi(RB.x);  nb[10]=bflo(RB.y); nb[11]=bfhi(RB.y); \
        nb[12]=bflo(RB.z); nb[13]=bfhi(RB.z); nb[14]=bflo(RB.w); nb[15]=bfhi(RB.w); \
        float h[FF];                                                         \
        _Pragma("unroll")                                                    \
        for (int g = 0; g < FF; ++g)                                         \
            h[g] = fmaf(DK, W1[2 * DD * FF + g], base[g]);                   \
        _Pragma("unroll")                                                    \
        for (int d = 0; d < DD; ++d) {                                       \
            const float x = nb[d];                                           \
            _Pragma("unroll")                                                \
            for (int g = 0; g < FF; ++g)                                     \
                h[g] = fmaf(x, W1[(DD + d) * FF + g], h[g]);                 \
        }                                                                    \
        _Pragma("unroll")                                                    \
        for (int g = 0; g < FF; ++g) hsum[g] += leakyf(h[g]);                \
    }

    DO_NB(ra0, rb0, dq.x)
    DO_NB(ra1, rb1, dq.y)
    DO_NB(ra2, rb2, dq.z)
    DO_NB(ra3, rb3, dq.w)
#undef DO_NB

    // ---- partial messages: pm[d] = sum_g hsum[g] * W2[g][d]  (W2 uniform -> SGPR) ----
    float pm[DD];
#pragma unroll
    for (int d = 0; d < DD; ++d) pm[d] = 0.0f;
#pragma unroll
    for (int g = 0; g < FF; ++g) {
        const float x = hsum[g];
#pragma unroll
        for (int d = 0; d < DD; ++d)
            pm[d] = fmaf(x, W2[g * DD + d], pm[d]);
    }

    // ---- reduce over the 4 lanes of this node (lanes 4n..4n+3, same wave) ----
#pragma unroll
    for (int d = 0; d < DD; ++d) {
        pm[d] += __shfl_xor(pm[d], 1);
        pm[d] += __shfl_xor(pm[d], 2);
        pm[d] = fmaf((float)KK, bb2[d], pm[d]);   // + K * b2
    }

    // ---- group norm (2 groups of 8) + leaky + residual (all lanes redundantly) ----
    float outv[DD];
#pragma unroll
    for (int grp = 0; grp < 2; ++grp) {
        float mu = 0.0f;
#pragma unroll
        for (int c = 0; c < 8; ++c) mu += pm[grp * 8 + c];
        mu *= 0.125f;
        float var = 0.0f;
#pragma unroll
        for (int c = 0; c < 8; ++c) {
            const float dv = pm[grp * 8 + c] - mu;
            var = fmaf(dv, dv, var);
        }
        var *= 0.125f;
        const float rinv = rsqrtf(var + EPSV);
#pragma unroll
        for (int c = 0; c < 8; ++c) {
            const int ch = grp * 8 + c;
            const float xn = (pm[ch] - mu) * rinv;
            outv[ch] = self_[ch] + leakyf(fmaf(xn, gnw[ch], gnb[ch]));
        }
    }

    // ---- select this lane's quarter (branchless) and store 16B fp32 + 8B bf16 ----
    const bool c1 = (s == 1), c2 = (s == 2), c3 = (s == 3);
    float o[4];
#pragma unroll
    for (int j = 0; j < 4; ++j)
        o[j] = c3 ? outv[12 + j] : (c2 ? outv[8 + j] : (c1 ? outv[4 + j] : outv[j]));

    float4 of; of.x = o[0]; of.y = o[1]; of.z = o[2]; of.w = o[3];
    *reinterpret_cast<float4*>(resid + (size_t)n * DD + s * 4) = of;

    ushort4 tb;
    tb.x = f2bf(o[0]); tb.y = f2bf(o[1]); tb.z = f2bf(o[2]); tb.w = f2bf(o[3]);
    *reinterpret_cast<ushort4*>(tout + (size_t)n * DD + s * 4) = tb;
}

extern "C" void kernel_launch(void* const* d_in, const int* in_sizes, int n_in,
                              void* d_out, int out_size, void* d_ws, size_t ws_size,
                              hipStream_t stream) {
    const float* y     = (const float*)d_in[0];   // N x D
    const float* dists = (const float*)d_in[1];   // N x K
    const float* W1    = (const float*)d_in[2];   // L x F x F
    const float* b1    = (const float*)d_in[3];   // L x F
    const float* W2    = (const float*)d_in[4];   // L x F x D
    const float* b2    = (const float*)d_in[5];   // L x D
    const float* gnw   = (const float*)d_in[6];   // L x D
    const float* gnb   = (const float*)d_in[7];   // L x D
    const int*   idx   = (const int*)d_in[8];     // N x K (int32 upload)

    float* resid = (float*)d_out;                           // fp32 residual, in-place
    unsigned short* tbl0 = (unsigned short*)d_ws;           // N x D bf16
    unsigned short* tbl1 = tbl0 + (size_t)NN * DD;          // N x D bf16  (12.8 MB total)

    const int block = 256;
    const int gridp = (NN * 4 + block - 1) / block;         // 3125 (exact)

    prep_kernel<<<gridp, block, 0, stream>>>(y, resid, tbl0);

    // layer 0: gathers from tbl0, writes tbl1 ; layer 1: tbl1 -> tbl0 ; layer 2: tbl0 -> tbl1
    layer_kernel<<<gridp, block, 0, stream>>>(
        resid, tbl0, tbl1, dists, idx,
        W1 + 0 * FF * FF, b1 + 0 * FF, W2 + 0 * FF * DD, b2 + 0 * DD,
        gnw + 0 * DD, gnb + 0 * DD);

    layer_kernel<<<gridp, block, 0, stream>>>(
        resid, tbl1, tbl0, dists, idx,
        W1 + 1 * FF * FF, b1 + 1 * FF, W2 + 1 * FF * DD, b2 + 1 * DD,
        gnw + 1 * DD, gnb + 1 * DD);

    layer_kernel<<<gridp, block, 0, stream>>>(
        resid, tbl0, tbl1, dists, idx,
        W1 + 2 * FF * FF, b1 + 2 * FF, W2 + 2 * FF * DD, b2 + 2 * DD,
        gnw + 2 * DD, gnb + 2 * DD);
}

// Round 3
// 283.447 us; speedup vs baseline: 2.6880x; 2.6880x over previous
//
#include <hip/hip_runtime.h>

#define NN 200000
#define DD 16
#define KK 16
#define FF 33   // 2*DD + 1

typedef __attribute__((ext_vector_type(8))) short bf16x8;
typedef __attribute__((ext_vector_type(4))) float f32x4;

__device__ __forceinline__ float leakyf(float v) { return fmaxf(v, 0.2f * v); }

// fp32 -> bf16 bits, round-to-nearest-even (works for negatives: carry never flips sign here)
__device__ __forceinline__ unsigned short f2bf(float f) {
    unsigned u = __float_as_uint(f);
    u += 0x7FFFu + ((u >> 16) & 1u);
    return (unsigned short)(u >> 16);
}
__device__ __forceinline__ float bf2f(unsigned short h) {
    return __uint_as_float(((unsigned)h) << 16);
}

// ---- pre-pass: residual(d_out) = y ; tbl0 = bf16(y) ----
__global__ __launch_bounds__(256) void prep_kernel(
    const float* __restrict__ y, float* __restrict__ resid,
    unsigned short* __restrict__ tbl)
{
    const int i = blockIdx.x * 256 + threadIdx.x;   // 800000 float4-groups, exact
    const float4 v = reinterpret_cast<const float4*>(y)[i];
    reinterpret_cast<float4*>(resid)[i] = v;
    ushort4 t;
    t.x = f2bf(v.x); t.y = f2bf(v.y); t.z = f2bf(v.z); t.w = f2bf(v.w);
    reinterpret_cast<ushort4*>(tbl)[i] = t;
}

// ============================================================================
// MFMA layer kernel. One wave = 16 nodes.
// Stage 1 (per node): h[k=16][g=33] via mfma_f32_16x16x32_bf16:
//   A[k][f=0..31] = [self(16) | nb_k(16)]  (one 16B lane load: groups 0/1 self,
//   groups 2/3 gathered neighbor row), B = W1[f][g] fragments held in VGPRs
//   (hi+lo bf16 split), C-init = b1[g] + d[n][k]*W1[32][g] (fp32).
//   leaky + k-sum (3 adds + shfl_xor 16/32) -> hsum[g], stored hi/lo bf16 in LDS.
// Stage 2 (per 16 nodes): msg = hsum @ W2 (+16*b2) via 6 MFMAs (hi/lo), then
//   group-norm with 8-lane butterflies, residual add in-place, bf16 table out.
// ============================================================================
__global__ __launch_bounds__(256) void layer_kernel(
    float*       __restrict__ resid,          // N x D fp32 (in-place residual)
    const unsigned short* __restrict__ tin,   // N x D bf16 (prev layer, gathers)
    unsigned short*       __restrict__ tout,  // N x D bf16 (this layer)
    const float* __restrict__ dists,          // N x K
    const int*   __restrict__ idx,            // N x K
    const float* __restrict__ W1,             // F x F
    const float* __restrict__ b1,             // F
    const float* __restrict__ W2,             // F x D
    const float* __restrict__ b2,             // D
    const float* __restrict__ gnw,            // D
    const float* __restrict__ gnb)            // D
{
    __shared__ __align__(16) unsigned short hsH[4][16][64];
    __shared__ __align__(16) unsigned short hsL[4][16][64];

    const int tid  = threadIdx.x;
    const int w    = tid >> 6;        // wave in block
    const int l    = tid & 63;        // lane
    const int g4   = l >> 4;          // 16-lane group 0..3
    const int c16  = l & 15;
    const int n0   = (blockIdx.x * 4 + w) * 16;   // first node of this wave's batch

    // ---- zero LDS (pad columns must be 0 for the stage-2 MFMA) ----
    {
        uint4 z; z.x = z.y = z.z = z.w = 0u;
#pragma unroll
        for (int t = 0; t < 2; ++t) {
            reinterpret_cast<uint4*>(&hsH[w][0][0])[l + 64 * t] = z;
            reinterpret_cast<uint4*>(&hsL[w][0][0])[l + 64 * t] = z;
        }
    }

    // ---- W1 B-fragments (held in VGPRs for the whole kernel), hi+lo split ----
    // B[f][g]: lane holds col g = c16+16*gt, rows f = 8*g4+j (f=0..15 self, 16..31 nb)
    bf16x8 bW1h0, bW1h1, bW1h2, bW1l0, bW1l1, bW1l2;
    float  w1l0, w1l1, w1l2, b1v0, b1v1, b1v2;
#define LOAD_W1(GT, BH, BL, WL, BV)                                    \
    {                                                                  \
        const int g = c16 + 16 * GT;                                   \
        const bool gv = (g < FF);                                      \
        _Pragma("unroll")                                              \
        for (int j = 0; j < 8; ++j) {                                  \
            const int f = 8 * g4 + j;                                  \
            const float wv = gv ? W1[f * FF + g] : 0.f;                \
            const unsigned short hi = f2bf(wv);                        \
            BH[j] = (short)hi;                                         \
            BL[j] = (short)f2bf(wv - bf2f(hi));                        \
        }                                                              \
        WL = gv ? W1[32 * FF + g] : 0.f;                               \
        BV = gv ? b1[g] : 0.f;                                         \
    }
    LOAD_W1(0, bW1h0, bW1l0, w1l0, b1v0)
    LOAD_W1(1, bW1h1, bW1l1, w1l1, b1v1)
    LOAD_W1(2, bW1h2, bW1l2, w1l2, b1v2)
#undef LOAD_W1

    // ---- W2 B-fragments: B[g][d]: col d = c16, rows g = 8*g4+j (+32 for step b) ----
    bf16x8 b2ah, b2al, b2bh, b2bl;
#pragma unroll
    for (int j = 0; j < 8; ++j) {
        const float wa = W2[(8 * g4 + j) * DD + c16];
        const unsigned short ha = f2bf(wa);
        b2ah[j] = (short)ha;
        b2al[j] = (short)f2bf(wa - bf2f(ha));
        const float wb = (g4 == 0 && j == 0) ? W2[32 * DD + c16] : 0.f;
        const unsigned short hb = f2bf(wb);
        b2bh[j] = (short)hb;
        b2bl[j] = (short)f2bf(wb - bf2f(hb));
    }
    const float kb2 = 16.f * b2[c16];
    const float gw  = gnw[c16];
    const float gb  = gnb[c16];

    // ---- stage 1: 16 nodes, software-pipelined (idx 2 ahead, A/dists 1 ahead) ----
    int nbi_nxt = idx[(size_t)n0 * KK + c16];
    {
        const int arow0 = (g4 >= 2) ? nbi_nxt : n0;
        // (first A load depends on first idx load; unavoidable once)
        nbi_nxt = idx[(size_t)(n0 + 1) * KK + c16];
        // fallthrough into loop state below
        // av_cur/dq_cur initialized here:
        // (declared outside the block)
        (void)arow0;
    }
    bf16x8 av_cur;
    float4 dq_cur;
    {
        const int nbi0 = idx[(size_t)n0 * KK + c16];
        const int arow = (g4 >= 2) ? nbi0 : n0;
        av_cur = *reinterpret_cast<const bf16x8*>(tin + (size_t)arow * DD + (g4 & 1) * 8);
        dq_cur = *reinterpret_cast<const float4*>(dists + (size_t)n0 * KK + g4 * 4);
    }

#pragma unroll 1
    for (int m = 0; m < 16; ++m) {
        const bf16x8 av = av_cur;
        const float4 dq = dq_cur;
        if (m < 15) {
            const int arow = (g4 >= 2) ? nbi_nxt : (n0 + m + 1);
            av_cur = *reinterpret_cast<const bf16x8*>(tin + (size_t)arow * DD + (g4 & 1) * 8);
            dq_cur = *reinterpret_cast<const float4*>(dists + (size_t)(n0 + m + 1) * KK + g4 * 4);
            if (m < 14)
                nbi_nxt = idx[(size_t)(n0 + m + 2) * KK + c16];
        }

        // C-init: acc[j] = b1[g] + d[n][k=4*g4+j] * W1[32][g]
        f32x4 acc0, acc1, acc2;
        acc0[0] = fmaf(dq.x, w1l0, b1v0); acc0[1] = fmaf(dq.y, w1l0, b1v0);
        acc0[2] = fmaf(dq.z, w1l0, b1v0); acc0[3] = fmaf(dq.w, w1l0, b1v0);
        acc1[0] = fmaf(dq.x, w1l1, b1v1); acc1[1] = fmaf(dq.y, w1l1, b1v1);
        acc1[2] = fmaf(dq.z, w1l1, b1v1); acc1[3] = fmaf(dq.w, w1l1, b1v1);
        acc2[0] = fmaf(dq.x, w1l2, b1v2); acc2[1] = fmaf(dq.y, w1l2, b1v2);
        acc2[2] = fmaf(dq.z, w1l2, b1v2); acc2[3] = fmaf(dq.w, w1l2, b1v2);

        acc0 = __builtin_amdgcn_mfma_f32_16x16x32_bf16(av, bW1h0, acc0, 0, 0, 0);
        acc1 = __builtin_amdgcn_mfma_f32_16x16x32_bf16(av, bW1h1, acc1, 0, 0, 0);
        acc2 = __builtin_amdgcn_mfma_f32_16x16x32_bf16(av, bW1h2, acc2, 0, 0, 0);
        acc0 = __builtin_amdgcn_mfma_f32_16x16x32_bf16(av, bW1l0, acc0, 0, 0, 0);
        acc1 = __builtin_amdgcn_mfma_f32_16x16x32_bf16(av, bW1l1, acc1, 0, 0, 0);
        acc2 = __builtin_amdgcn_mfma_f32_16x16x32_bf16(av, bW1l2, acc2, 0, 0, 0);

        // leaky + sum over k (4 regs in-lane, then the two l>>4 bits)
        float s0 = leakyf(acc0[0]) + leakyf(acc0[1]) + leakyf(acc0[2]) + leakyf(acc0[3]);
        float s1 = leakyf(acc1[0]) + leakyf(acc1[1]) + leakyf(acc1[2]) + leakyf(acc1[3]);
        float s2 = leakyf(acc2[0]) + leakyf(acc2[1]) + leakyf(acc2[2]) + leakyf(acc2[3]);
        s0 += __shfl_xor(s0, 16); s0 += __shfl_xor(s0, 32);
        s1 += __shfl_xor(s1, 16); s1 += __shfl_xor(s1, 32);
        s2 += __shfl_xor(s2, 16); s2 += __shfl_xor(s2, 32);

        // hsum -> LDS (hi + lo bf16), XOR-swizzled columns (T2) by node row
        if (g4 == 0) {
            const int sw = (m & 7) << 3;
            const unsigned short h0 = f2bf(s0);
            const unsigned short h1 = f2bf(s1);
            const unsigned short h2 = f2bf(s2);
            hsH[w][m][(c16     ) ^ sw] = h0;
            hsH[w][m][(c16 + 16) ^ sw] = h1;
            hsH[w][m][(c16 + 32) ^ sw] = h2;
            hsL[w][m][(c16     ) ^ sw] = f2bf(s0 - bf2f(h0));
            hsL[w][m][(c16 + 16) ^ sw] = f2bf(s1 - bf2f(h1));
            hsL[w][m][(c16 + 32) ^ sw] = f2bf(s2 - bf2f(h2));
        }
    }

    // ---- stage 2: msg[node][d] = hsum @ W2 + 16*b2  (A rows = node = c16) ----
    const int swr = (c16 & 7) << 3;
    const unsigned short* rowH = &hsH[w][c16][0];
    const unsigned short* rowL = &hsL[w][c16][0];
    const bf16x8 a2h0 = *reinterpret_cast<const bf16x8*>(rowH + ((8 * g4     ) ^ swr));
    const bf16x8 a2h1 = *reinterpret_cast<const bf16x8*>(rowH + ((8 * g4 + 32) ^ swr));
    const bf16x8 a2l0 = *reinterpret_cast<const bf16x8*>(rowL + ((8 * g4     ) ^ swr));
    const bf16x8 a2l1 = *reinterpret_cast<const bf16x8*>(rowL + ((8 * g4 + 32) ^ swr));

    f32x4 macc;
    macc[0] = kb2; macc[1] = kb2; macc[2] = kb2; macc[3] = kb2;
    macc = __builtin_amdgcn_mfma_f32_16x16x32_bf16(a2h0, b2ah, macc, 0, 0, 0);
    macc = __builtin_amdgcn_mfma_f32_16x16x32_bf16(a2h1, b2bh, macc, 0, 0, 0);
    macc = __builtin_amdgcn_mfma_f32_16x16x32_bf16(a2l0, b2ah, macc, 0, 0, 0);
    macc = __builtin_amdgcn_mfma_f32_16x16x32_bf16(a2l1, b2bh, macc, 0, 0, 0);
    macc = __builtin_amdgcn_mfma_f32_16x16x32_bf16(a2h0, b2al, macc, 0, 0, 0);
    macc = __builtin_amdgcn_mfma_f32_16x16x32_bf16(a2h1, b2bl, macc, 0, 0, 0);

    // ---- group-norm + leaky + residual; D2: col d=c16, row node=4*g4+reg ----
#pragma unroll
    for (int j = 0; j < 4; ++j) {
        const float v = macc[j];
        const int n = n0 + 4 * g4 + j;
        float mu = v;
        mu += __shfl_xor(mu, 1); mu += __shfl_xor(mu, 2); mu += __shfl_xor(mu, 4);
        mu *= 0.125f;
        const float e = v - mu;
        float s2 = e * e;
        s2 += __shfl_xor(s2, 1); s2 += __shfl_xor(s2, 2); s2 += __shfl_xor(s2, 4);
        s2 *= 0.125f;
        const float xn  = e * rsqrtf(s2 + 1e-5f);
        const float val = leakyf(fmaf(xn, gw, gb));
        const float r   = resid[(size_t)n * DD + c16];
        const float o   = r + val;
        resid[(size_t)n * DD + c16] = o;
        tout [(size_t)n * DD + c16] = f2bf(o);
    }
}

extern "C" void kernel_launch(void* const* d_in, const int* in_sizes, int n_in,
                              void* d_out, int out_size, void* d_ws, size_t ws_size,
                              hipStream_t stream) {
    const float* y     = (const float*)d_in[0];
    const float* dists = (const float*)d_in[1];
    const float* W1    = (const float*)d_in[2];
    const float* b1    = (const float*)d_in[3];
    const float* W2    = (const float*)d_in[4];
    const float* b2    = (const float*)d_in[5];
    const float* gnw   = (const float*)d_in[6];
    const float* gnb   = (const float*)d_in[7];
    const int*   idx   = (const int*)d_in[8];

    float* resid = (float*)d_out;                     // fp32 residual, in-place
    unsigned short* tbl0 = (unsigned short*)d_ws;     // N x D bf16
    unsigned short* tbl1 = tbl0 + (size_t)NN * DD;    // N x D bf16

    const int block = 256;
    prep_kernel<<<(NN * 4) / block, block, 0, stream>>>(y, resid, tbl0);

    const int grid = NN / 64;   // 3125 blocks; 4 waves/block x 16 nodes/wave

    layer_kernel<<<grid, block, 0, stream>>>(
        resid, tbl0, tbl1, dists, idx,
        W1 + 0 * FF * FF, b1 + 0 * FF, W2 + 0 * FF * DD, b2 + 0 * DD,
        gnw + 0 * DD, gnb + 0 * DD);

    layer_kernel<<<grid, block, 0, stream>>>(
        resid, tbl1, tbl0, dists, idx,
        W1 + 1 * FF * FF, b1 + 1 * FF, W2 + 1 * FF * DD, b2 + 1 * DD,
        gnw + 1 * DD, gnb + 1 * DD);

    layer_kernel<<<grid, block, 0, stream>>>(
        resid, tbl0, tbl1, dists, idx,
        W1 + 2 * FF * FF, b1 + 2 * FF, W2 + 2 * FF * DD, b2 + 2 * DD,
        gnw + 2 * DD, gnb + 2 * DD);
}

// Round 4
// 216.765 us; speedup vs baseline: 3.5149x; 1.3076x over previous
//
#include <hip/hip_runtime.h>

#define NN 200000
#define DD 16
#define KK 16
#define FF 33   // 2*DD + 1

typedef __attribute__((ext_vector_type(8))) short bf16x8;
typedef __attribute__((ext_vector_type(4))) float f32x4;

// fp32 -> bf16 bits, round-to-nearest-even
__device__ __forceinline__ unsigned short f2bf(float f) {
    unsigned u = __float_as_uint(f);
    u += 0x7FFFu + ((u >> 16) & 1u);
    return (unsigned short)(u >> 16);
}

// ---- pre-pass: residual(d_out) = y ; tbl0 = bf16(y) ----
__global__ __launch_bounds__(256) void prep_kernel(
    const float* __restrict__ y, float* __restrict__ resid,
    unsigned short* __restrict__ tbl)
{
    const unsigned i = blockIdx.x * 256 + threadIdx.x;   // 800000 exact
    const float4 v = reinterpret_cast<const float4*>(y)[i];
    reinterpret_cast<float4*>(resid)[i] = v;
    ushort4 t;
    t.x = f2bf(v.x); t.y = f2bf(v.y); t.z = f2bf(v.z); t.w = f2bf(v.w);
    reinterpret_cast<ushort4*>(tbl)[i] = t;
}

// ---- one-shot weight packing: per-lane MFMA fragments into ws ----
// Layout per layer (float4 units, stride WSTRIDE):
//   [  0..191] W1 B-frags t=0..2   (bf16x8 per lane)
//   [192..255] W2 B-frag a (g rows 0..31)
//   [256..319] W2 B-frag b (g rows 32..63, zero-padded)
//   [320..   ] floats: w1l0/1/2 (dist col of W1), b1v0/1/2   (6 x 64)
#define WSTRIDE 448

__global__ __launch_bounds__(64) void pack_kernel(
    const float* __restrict__ W1, const float* __restrict__ b1,
    const float* __restrict__ W2, float4* __restrict__ wpk)
{
    const int L = blockIdx.x, l = threadIdx.x, g4 = l >> 4, c16 = l & 15;
    const float* W1l = W1 + L * FF * FF;
    const float* W2l = W2 + L * FF * DD;
    float4* out = wpk + L * WSTRIDE;

#pragma unroll
    for (int t = 0; t < 3; ++t) {
        const int g = c16 + 16 * t;
        const bool gv = (g < FF);
        bf16x8 fr;
#pragma unroll
        for (int j = 0; j < 8; ++j) {
            const float wv = gv ? W1l[(8 * g4 + j) * FF + g] : 0.f;
            fr[j] = (short)f2bf(wv);
        }
        out[t * 64 + l] = __builtin_bit_cast(float4, fr);
    }
    {
        bf16x8 fa, fb;
#pragma unroll
        for (int j = 0; j < 8; ++j) {
            fa[j] = (short)f2bf(W2l[(8 * g4 + j) * DD + c16]);
            const int g = 32 + 8 * g4 + j;
            fb[j] = (short)((g < FF) ? f2bf(W2l[g * DD + c16]) : 0);
        }
        out[192 + l] = __builtin_bit_cast(float4, fa);
        out[256 + l] = __builtin_bit_cast(float4, fb);
    }
    float* wf = reinterpret_cast<float*>(out + 320);
#pragma unroll
    for (int t = 0; t < 3; ++t) {
        const int g = c16 + 16 * t;
        const bool gv = (g < FF);
        wf[t * 64 + l]       = gv ? W1l[32 * FF + g] : 0.f;
        wf[192 + t * 64 + l] = gv ? b1[L * FF + g]   : 0.f;
    }
}

// ---- one message-passing layer (structure as round 3, scaffolding minimized) ----
__global__ __launch_bounds__(256) void layer_kernel(
    float*       __restrict__ resid,          // N x D fp32 (in-place residual)
    const unsigned short* __restrict__ tin,   // N x D bf16 (prev layer)
    unsigned short*       __restrict__ tout,  // N x D bf16 (this layer)
    const float* __restrict__ dists,          // N x K
    const int*   __restrict__ idx,            // N x K
    const float4* __restrict__ wpkL,          // packed weights, this layer
    const float* __restrict__ b2,             // D
    const float* __restrict__ gnw,            // D
    const float* __restrict__ gnb)            // D
{
    __shared__ unsigned short hsH[4][16][64];

    const int tid = threadIdx.x;
    const int w   = tid >> 6, l = tid & 63, g4 = l >> 4, c16 = l & 15;
    const int n0  = (blockIdx.x * 4 + w) * 16;

    // zero this wave's LDS slice (pad cols must not be Inf/NaN garbage)
    {
        uint4 z; z.x = z.y = z.z = z.w = 0u;
        reinterpret_cast<uint4*>(&hsH[w][0][0])[l]      = z;
        reinterpret_cast<uint4*>(&hsH[w][0][0])[l + 64] = z;
    }

    // ---- fragment loads (all pre-packed, coalesced) ----
    const bf16x8* wv8 = reinterpret_cast<const bf16x8*>(wpkL);
    const bf16x8 bW1h0 = wv8[0 * 64 + l];
    const bf16x8 bW1h1 = wv8[1 * 64 + l];
    const bf16x8 bW1h2 = wv8[2 * 64 + l];
    const bf16x8 b2ah  = wv8[192 + l];
    const bf16x8 b2bh  = wv8[256 + l];
    const float* wf = reinterpret_cast<const float*>(wpkL + 320);
    const float w1l0 = wf[l], w1l1 = wf[64 + l], w1l2 = wf[128 + l];
    const float b1v0 = wf[192 + l], b1v1 = wf[256 + l], b1v2 = wf[320 + l];
    const float kb2 = 16.f * b2[c16];
    const float gw  = gnw[c16], gb = gnb[c16];

    const bf16x8* tinv = reinterpret_cast<const bf16x8*>(tin);
    const float4* dq4  = reinterpret_cast<const float4*>(dists);

    // ---- prologue: idx 4 rows ahead, A-fragment + dists 2 ahead ----
    int    nbp[4];
    bf16x8 avp[2];
    float4 dqp[2];
#pragma unroll
    for (int j = 0; j < 4; ++j)
        nbp[j] = idx[(unsigned)(n0 + j) * KK + c16];
#pragma unroll
    for (int j = 0; j < 2; ++j) {
        const unsigned ar = (g4 >= 2) ? (unsigned)nbp[j] : (unsigned)(n0 + j);
        avp[j] = tinv[ar * 2 + (g4 & 1)];
        dqp[j] = dq4[(unsigned)(n0 + j) * 4 + g4];
    }

#pragma unroll
    for (int m = 0; m < 16; ++m) {
        const bf16x8 a = avp[m & 1];
        const float4 q = dqp[m & 1];

        // prefetch row m+2 (A, dists) and idx row m+4; rows clamped (uniform SALU)
        {
            const int r2 = (n0 + m + 2 < NN) ? (n0 + m + 2) : (NN - 1);
            const unsigned ar = (g4 >= 2) ? (unsigned)nbp[(m + 2) & 3] : (unsigned)r2;
            avp[m & 1] = tinv[ar * 2 + (g4 & 1)];
            dqp[m & 1] = dq4[(unsigned)r2 * 4 + g4];
            const int r4 = (n0 + m + 4 < NN) ? (n0 + m + 4) : (NN - 1);
            nbp[m & 3] = idx[(unsigned)r4 * KK + c16];
        }

        // C-init: acc[j] = b1[g] + d[n][k=4*g4+j] * W1[32][g]
        f32x4 acc0, acc1, acc2;
        acc0[0] = fmaf(q.x, w1l0, b1v0); acc0[1] = fmaf(q.y, w1l0, b1v0);
        acc0[2] = fmaf(q.z, w1l0, b1v0); acc0[3] = fmaf(q.w, w1l0, b1v0);
        acc1[0] = fmaf(q.x, w1l1, b1v1); acc1[1] = fmaf(q.y, w1l1, b1v1);
        acc1[2] = fmaf(q.z, w1l1, b1v1); acc1[3] = fmaf(q.w, w1l1, b1v1);
        acc2[0] = fmaf(q.x, w1l2, b1v2); acc2[1] = fmaf(q.y, w1l2, b1v2);
        acc2[2] = fmaf(q.z, w1l2, b1v2); acc2[3] = fmaf(q.w, w1l2, b1v2);

        acc0 = __builtin_amdgcn_mfma_f32_16x16x32_bf16(a, bW1h0, acc0, 0, 0, 0);
        acc1 = __builtin_amdgcn_mfma_f32_16x16x32_bf16(a, bW1h1, acc1, 0, 0, 0);
        acc2 = __builtin_amdgcn_mfma_f32_16x16x32_bf16(a, bW1h2, acc2, 0, 0, 0);

        // sum_j leaky(x_j) = 0.6*sum x + 0.4*sum |x|   (|x| free as input mod)
        float sx0 = (acc0[0] + acc0[1]) + (acc0[2] + acc0[3]);
        float sa0 = (fabsf(acc0[0]) + fabsf(acc0[1])) + (fabsf(acc0[2]) + fabsf(acc0[3]));
        float sx1 = (acc1[0] + acc1[1]) + (acc1[2] + acc1[3]);
        float sa1 = (fabsf(acc1[0]) + fabsf(acc1[1])) + (fabsf(acc1[2]) + fabsf(acc1[3]));
        float sx2 = (acc2[0] + acc2[1]) + (acc2[2] + acc2[3]);
        float sa2 = (fabsf(acc2[0]) + fabsf(acc2[1])) + (fabsf(acc2[2]) + fabsf(acc2[3]));
        float s0 = fmaf(0.6f, sx0, 0.4f * sa0);
        float s1 = fmaf(0.6f, sx1, 0.4f * sa1);
        float s2 = fmaf(0.6f, sx2, 0.4f * sa2);
        s0 += __shfl_xor(s0, 16); s0 += __shfl_xor(s0, 32);
        s1 += __shfl_xor(s1, 16); s1 += __shfl_xor(s1, 32);
        s2 += __shfl_xor(s2, 16); s2 += __shfl_xor(s2, 32);

        // hsum -> LDS (hi bf16), one store per lane, groups 0..2; XOR-swizzled
        const float sv = (g4 == 0) ? s0 : ((g4 == 1) ? s1 : s2);
        if (g4 < 3)
            hsH[w][m][l ^ ((m & 7) << 3)] = f2bf(sv);
    }

    // ---- stage 2: msg = hsum @ W2 + 16*b2 ----
    const int swr = (c16 & 7) << 3;
    const unsigned short* rowH = &hsH[w][c16][0];
    const bf16x8 a2h0 = *reinterpret_cast<const bf16x8*>(rowH + ((8 * g4     ) ^ swr));
    const bf16x8 a2h1 = *reinterpret_cast<const bf16x8*>(rowH + ((8 * g4 + 32) ^ swr));

    f32x4 macc;
    macc[0] = kb2; macc[1] = kb2; macc[2] = kb2; macc[3] = kb2;
    macc = __builtin_amdgcn_mfma_f32_16x16x32_bf16(a2h0, b2ah, macc, 0, 0, 0);
    macc = __builtin_amdgcn_mfma_f32_16x16x32_bf16(a2h1, b2bh, macc, 0, 0, 0);

    // ---- group-norm + leaky + residual (in-place) + bf16 table out ----
#pragma unroll
    for (int j = 0; j < 4; ++j) {
        const float v = macc[j];
        const unsigned n = (unsigned)(n0 + 4 * g4 + j);
        float mu = v;
        mu += __shfl_xor(mu, 1); mu += __shfl_xor(mu, 2); mu += __shfl_xor(mu, 4);
        mu *= 0.125f;
        const float e = v - mu;
        float vr = e * e;
        vr += __shfl_xor(vr, 1); vr += __shfl_xor(vr, 2); vr += __shfl_xor(vr, 4);
        vr *= 0.125f;
        const float xn = e * rsqrtf(vr + 1e-5f);
        const float yv = fmaf(xn, gw, gb);
        const float val = fmaxf(yv, 0.2f * yv);
        const float o = resid[n * DD + c16] + val;
        resid[n * DD + c16] = o;
        tout [n * DD + c16] = f2bf(o);
    }
}

extern "C" void kernel_launch(void* const* d_in, const int* in_sizes, int n_in,
                              void* d_out, int out_size, void* d_ws, size_t ws_size,
                              hipStream_t stream) {
    const float* y     = (const float*)d_in[0];
    const float* dists = (const float*)d_in[1];
    const float* W1    = (const float*)d_in[2];
    const float* b1    = (const float*)d_in[3];
    const float* W2    = (const float*)d_in[4];
    const float* b2    = (const float*)d_in[5];
    const float* gnw   = (const float*)d_in[6];
    const float* gnb   = (const float*)d_in[7];
    const int*   idx   = (const int*)d_in[8];

    float* resid = (float*)d_out;                       // fp32 residual, in-place
    unsigned short* tbl0 = (unsigned short*)d_ws;       // N x D bf16
    unsigned short* tbl1 = tbl0 + (size_t)NN * DD;      // N x D bf16
    float4* wpk = (float4*)((char*)d_ws + (size_t)2 * NN * DD * 2);  // 21 KB packed weights

    pack_kernel<<<3, 64, 0, stream>>>(W1, b1, W2, wpk);
    prep_kernel<<<(NN * 4) / 256, 256, 0, stream>>>(y, resid, tbl0);

    const int grid = NN / 64;   // 3125 blocks; 4 waves x 16 nodes

    layer_kernel<<<grid, 256, 0, stream>>>(
        resid, tbl0, tbl1, dists, idx, wpk + 0 * WSTRIDE,
        b2 + 0 * DD, gnw + 0 * DD, gnb + 0 * DD);

    layer_kernel<<<grid, 256, 0, stream>>>(
        resid, tbl1, tbl0, dists, idx, wpk + 1 * WSTRIDE,
        b2 + 1 * DD, gnw + 1 * DD, gnb + 1 * DD);

    layer_kernel<<<grid, 256, 0, stream>>>(
        resid, tbl0, tbl1, dists, idx, wpk + 2 * WSTRIDE,
        b2 + 2 * DD, gnw + 2 * DD, gnb + 2 * DD);
}